// Round 8
// baseline (380.233 us; speedup 1.0000x reference)
//
#include <hip/hip_runtime.h>
#include <stdint.h>

// Problem constants (from reference)
#define NB   4      // batch
#define CC   256    // channels (K)
#define WR   60     // cells per row/col
#define MM   3600   // HR*WR (M and N of the GEMM)
#define HH   480
#define WW   480
#define GS   8
#define MT   29     // ceil(3600/128) tiles per side
#define NBLK (MT * MT * NB)      // gemm grid size = 3364
#define PREPB 57                 // ceil(NB*MM / 256) blocks carrying prep work

typedef float f32x4 __attribute__((ext_vector_type(4)));
typedef long  l64x2 __attribute__((ext_vector_type(2)));

// ---------------------------------------------------------------------------
// Kernel 1: pack desc[b][c][m] (f32) into PAIR-INTERLEAVED MFMA-fragment
// fp8-e4m3 tiles (4 KB per [b][mtile][kt]):
//   addr = tile_base + h*2048 + p*1024 + lane*16
//   bytes [0..8) = frag t=2p   lane data, bytes [8..16) = frag t=2p+1
// where frag t covers m = mtile*128 + h*64 + t*16 + (lane&15),
//                     k = kt*32 + (lane>>4)*8 + e.
// The GEMM thus loads each A/B kt-operand with 2 global_load_dwordx4 per
// lane (16 B sweet spot) straight into registers — no LDS. Tail rows
// zero-filled. FUSED: blocks 0..56 do per-cell prep (homography warp,
// vis 8x8 product, per-block vm partials).
// ---------------------------------------------------------------------------
__global__ __launch_bounds__(256) void pack_prep(
    const float* __restrict__ d1, const float* __restrict__ d2,
    const float* __restrict__ homo, const float* __restrict__ vis,
    unsigned char* __restrict__ p1, unsigned char* __restrict__ p2,
    float2* __restrict__ wg, float* __restrict__ vmarr,
    float* __restrict__ vm_part) {
  __shared__ float tile[32][132];   // [k_local][m_local]; rows 528B (16B-aligned)
  int kt = blockIdx.x, mtile = blockIdx.y, z = blockIdx.z;
  int bid = kt + 8 * (mtile + MT * z);
  int b = z & 3;
  const float* src = ((z >> 2) ? d2 : d1) + (size_t)b * CC * MM + (size_t)(kt * 32) * MM;
  unsigned char* dst = ((z >> 2) ? p2 : p1) + ((size_t)(b * MT + mtile) * 8 + kt) * 4096;
  int tid = threadIdx.x;

  // coalesced read: 32 k-rows x 128 m (float4 along m)
#pragma unroll
  for (int pass = 0; pass < 4; ++pass) {
    int cid = pass * 256 + tid;          // [0,1024)
    int c = cid >> 5, m4 = (cid & 31) * 4;
    int gm = mtile * 128 + m4;
    float4 v;
    if (gm + 3 < MM) {
      v = *(const float4*)(src + (size_t)c * MM + gm);
    } else {
      v.x = (gm     < MM) ? src[(size_t)c * MM + gm]     : 0.f;
      v.y = (gm + 1 < MM) ? src[(size_t)c * MM + gm + 1] : 0.f;
      v.z = (gm + 2 < MM) ? src[(size_t)c * MM + gm + 2] : 0.f;
      v.w = (gm + 3 < MM) ? src[(size_t)c * MM + gm + 3] : 0.f;
    }
    *(float4*)&tile[c][m4] = v;
  }
  __syncthreads();

  // pair-interleaved fragment write: 256 slots x 16B, one pass.
  // slot s: lane = s&63, p = (s>>6)&1, h = s>>7.
  {
    int s = tid;
    int lane = s & 63, p = (s >> 6) & 1, h = s >> 7;
    int k_local = (lane >> 4) * 8;
    uint4 o;
    unsigned ww[4];
#pragma unroll
    for (int j = 0; j < 2; ++j) {
      int m_local = h * 64 + (2 * p + j) * 16 + (lane & 15);
      unsigned w01 = 0, w23 = 0;
      if (mtile * 128 + m_local < MM) {
        float f0 = tile[k_local + 0][m_local], f1 = tile[k_local + 1][m_local];
        float f2 = tile[k_local + 2][m_local], f3 = tile[k_local + 3][m_local];
        float f4 = tile[k_local + 4][m_local], f5 = tile[k_local + 5][m_local];
        float f6 = tile[k_local + 6][m_local], f7 = tile[k_local + 7][m_local];
        w01 = __builtin_amdgcn_cvt_pk_fp8_f32(f0, f1, 0, false);
        w01 = __builtin_amdgcn_cvt_pk_fp8_f32(f2, f3, w01, true);
        w23 = __builtin_amdgcn_cvt_pk_fp8_f32(f4, f5, 0, false);
        w23 = __builtin_amdgcn_cvt_pk_fp8_f32(f6, f7, w23, true);
      }
      ww[2 * j]     = w01;
      ww[2 * j + 1] = w23;
    }
    o.x = ww[0]; o.y = ww[1]; o.z = ww[2]; o.w = ww[3];
    ((uint4*)dst)[s] = o;
  }

  // ---- fused prep (blocks 0..56 only; block-uniform branch) ----
  if (bid < PREPB) {
    int idx = bid * 256 + tid;
    float p = 0.f;
    if (idx < NB * MM) {
      int bb = idx / MM, cell = idx - bb * MM;
      int h1 = cell / WR, w1 = cell - h1 * WR;
      float gx = (float)(w1 * GS + GS / 2);
      float gy = (float)(h1 * GS + GS / 2);
      const float* Hm = homo + bb * 9;
      float X = Hm[0] * gx + Hm[1] * gy + Hm[2];
      float Y = Hm[3] * gx + Hm[4] * gy + Hm[5];
      float Z = Hm[6] * gx + Hm[7] * gy + Hm[8];
      wg[idx] = make_float2(X / Z, Y / Z);
      const float* v = vis + (size_t)bb * HH * WW + (size_t)(h1 * GS) * WW + w1 * GS;
      float prod = 1.f;
#pragma unroll
      for (int rr = 0; rr < GS; ++rr) {
        const float4* rp = (const float4*)(v + (size_t)rr * WW);
        float4 a = rp[0], c = rp[1];
        prod *= a.x * a.y * a.z * a.w;
        prod *= c.x * c.y * c.z * c.w;
      }
      vmarr[idx] = prod;
      p = prod;
    }
#pragma unroll
    for (int off = 32; off; off >>= 1) p += __shfl_down(p, off, 64);
    __syncthreads();                      // tile LDS reuse safety
    if ((tid & 63) == 0) ((float*)tile)[tid >> 6] = p;
    __syncthreads();
    if (tid == 0)
      vm_part[bid] = ((float*)tile)[0] + ((float*)tile)[1] +
                     ((float*)tile)[2] + ((float*)tile)[3];
  }
}

// ---------------------------------------------------------------------------
// Kernel 2: fp8 MFMA GEMM + hinge loss. No LDS, no K-loop barriers, no
// contended atomics (round-7 fix; blocks write private partial slots).
// Round-8: pair-interleaved fragments -> 4 global_load_dwordx4 per lane
// per kt (was 8 dwordx2); launch_bounds(256,8) for 8 waves/SIMD TLP.
// ---------------------------------------------------------------------------
__global__ __launch_bounds__(256, 8) void hinge_gemm(
    const unsigned char* __restrict__ Ap, const unsigned char* __restrict__ Bp,
    const float2* __restrict__ wg, const float* __restrict__ vmarr,
    float* __restrict__ block_part) {
  __shared__ float partial[4];

  int b = blockIdx.z, mtile = blockIdx.y, ntile = blockIdx.x;
  int tid = threadIdx.x, lane = tid & 63, w = tid >> 6;
  int quad = lane >> 4, r = lane & 15;
  int wave_m = w >> 1, wave_n = w & 1;

  // per-lane fragment-pair base: pair p of kt at base + kt*4096 + p*1024
  const char* Af = (const char*)Ap + ((size_t)(b * MT + mtile) * 8) * 4096
                   + wave_m * 2048 + lane * 16;
  const char* Bf = (const char*)Bp + ((size_t)(b * MT + ntile) * 8) * 4096
                   + wave_n * 2048 + lane * 16;

  f32x4 acc[4][4];
#pragma unroll
  for (int i = 0; i < 4; ++i)
#pragma unroll
    for (int j = 0; j < 4; ++j)
#pragma unroll
      for (int k = 0; k < 4; ++k) acc[i][j][k] = 0.f;

  long a0[4], b0[4], a1[4], b1[4];
#pragma unroll
  for (int p = 0; p < 2; ++p) {
    l64x2 va = *(const l64x2*)(Af + p * 1024);
    l64x2 vb = *(const l64x2*)(Bf + p * 1024);
    a0[2 * p] = va.x; a0[2 * p + 1] = va.y;
    b0[2 * p] = vb.x; b0[2 * p + 1] = vb.y;
  }

#pragma unroll
  for (int kt = 0; kt < 8; ++kt) {
    if (kt < 7) {   // prefetch kt+1 fragment-pairs into shadow registers
      const char* an = Af + (kt + 1) * 4096;
      const char* bn = Bf + (kt + 1) * 4096;
#pragma unroll
      for (int p = 0; p < 2; ++p) {
        l64x2 va = *(const l64x2*)(an + p * 1024);
        l64x2 vb = *(const l64x2*)(bn + p * 1024);
        a1[2 * p] = va.x; a1[2 * p + 1] = va.y;
        b1[2 * p] = vb.x; b1[2 * p + 1] = vb.y;
      }
    }
#pragma unroll
    for (int mt = 0; mt < 4; ++mt)
#pragma unroll
      for (int nt = 0; nt < 4; ++nt)
        acc[mt][nt] = __builtin_amdgcn_mfma_f32_16x16x32_fp8_fp8(
            a0[mt], b0[nt], acc[mt][nt], 0, 0, 0);
#pragma unroll
    for (int t = 0; t < 4; ++t) { a0[t] = a1[t]; b0[t] = b1[t]; }
  }

  // Epilogue. C/D layout: col(n) = lane&15, row(m) = quad*4 + reg.
  // Tail m-rows are zero-padded in Ap -> dot=0 -> hinge=0; no m-guard needed.
  float gxv[16], gyv[16];
#pragma unroll
  for (int mt = 0; mt < 4; ++mt)
#pragma unroll
    for (int reg = 0; reg < 4; ++reg) {
      int gm = mtile * 128 + wave_m * 64 + mt * 16 + quad * 4 + reg;
      float gmf = (float)gm;
      float h1 = floorf(fmaf(gmf, (1.0f / 60.0f), (1.0f / 120.0f)));
      float w1 = fmaf(h1, -60.f, gmf);
      gxv[mt * 4 + reg] = fmaf(w1, 8.f, 4.f);
      gyv[mt * 4 + reg] = fmaf(h1, 8.f, 4.f);
    }

  float sum = 0.f;
  const float2* wgb = wg + (size_t)b * MM;
  const float*  vmb = vmarr + (size_t)b * MM;
#pragma unroll
  for (int nt = 0; nt < 4; ++nt) {
    int gn = ntile * 128 + wave_n * 64 + nt * 16 + r;
    bool nok = gn < MM;
    float2 wgv = nok ? wgb[gn] : make_float2(1e9f, 1e9f);
    float  vmv = nok ? vmb[gn] : 0.f;
#pragma unroll
    for (int mt = 0; mt < 4; ++mt)
#pragma unroll
      for (int reg = 0; reg < 4; ++reg) {
        float dot = acc[mt][nt][reg];
        float dx = gxv[mt * 4 + reg] - wgv.x;
        float dy = gyv[mt * 4 + reg] - wgv.y;
        float d2 = fmaf(dx, dx, dy * dy);
        float a = (d2 <= 56.25f) ? (1.0f - dot) : (dot - 0.2f);
        sum = fmaf(vmv, fmaxf(a, 0.f), sum);
      }
  }
#pragma unroll
  for (int off = 32; off; off >>= 1) sum += __shfl_down(sum, off, 64);
  if (lane == 0) partial[w] = sum;
  __syncthreads();
  if (tid == 0) {
    int fbid = ntile + MT * (mtile + MT * b);
    block_part[fbid] = partial[0] + partial[1] + partial[2] + partial[3];
  }
}

// ---------------------------------------------------------------------------
// Kernel 3: reduce 3364 block partials + 57 vm partials; write output.
// ---------------------------------------------------------------------------
__global__ __launch_bounds__(256) void finalize_k(
    const float* __restrict__ block_part, const float* __restrict__ vm_part,
    float* __restrict__ out) {
  __shared__ float red[8];
  int tid = threadIdx.x;
  float s = 0.f, v = 0.f;
  for (int i = tid; i < NBLK; i += 256) s += block_part[i];
  if (tid < PREPB) v = vm_part[tid];
#pragma unroll
  for (int off = 32; off; off >>= 1) {
    s += __shfl_down(s, off, 64);
    v += __shfl_down(v, off, 64);
  }
  if ((tid & 63) == 0) { red[tid >> 6] = s; red[4 + (tid >> 6)] = v; }
  __syncthreads();
  if (tid == 0) {
    float S = red[0] + red[1] + red[2] + red[3];
    float V = red[4] + red[5] + red[6] + red[7];
    out[0] = S / ((float)MM * V);
  }
}

extern "C" void kernel_launch(void* const* d_in, const int* in_sizes, int n_in,
                              void* d_out, int out_size, void* d_ws, size_t ws_size,
                              hipStream_t stream) {
  const float* desc1 = (const float*)d_in[0];
  const float* desc2 = (const float*)d_in[1];
  const float* homo  = (const float*)d_in[2];
  const float* vis   = (const float*)d_in[3];
  float* out = (float*)d_out;

  char* ws = (char*)d_ws;
  // packed size per desc: 4 * 29 * 8 * 4096 B = 3,801,088 B
  unsigned char* Ap = (unsigned char*)ws;
  unsigned char* Bp = (unsigned char*)(ws + 3801088);
  float2* wg         = (float2*)(ws + 7602176);          // 115,200 B
  float*  vm         = (float*) (ws + 7717376);          //  57,600 B
  float*  vm_part    = (float*) (ws + 7774976);          // 57 * 4 B
  float*  block_part = (float*) (ws + 7775232);          // 3364 * 4 B

  dim3 pgrid(8, MT, 2 * NB);   // kt x mtile x (desc,b); fused prep
  pack_prep<<<pgrid, 256, 0, stream>>>(desc1, desc2, homo, vis, Ap, Bp,
                                       wg, vm, vm_part);

  dim3 ggrid(MT, MT, NB);
  hinge_gemm<<<ggrid, 256, 0, stream>>>(Ap, Bp, wg, vm, block_part);

  finalize_k<<<1, 256, 0, stream>>>(block_part, vm_part, out);
}

// Round 9
// 117.671 us; speedup vs baseline: 3.2313x; 3.2313x over previous
//
#include <hip/hip_runtime.h>
#include <stdint.h>

// Problem constants (from reference)
#define NB   4      // batch
#define CC   256    // channels (K)
#define WR   60     // cells per row/col
#define MM   3600   // HR*WR (M and N of the GEMM)
#define HH   480
#define WW   480
#define GS   8
#define MT   29     // ceil(3600/128) tiles per side
#define NBLK (MT * MT * NB)      // gemm grid size = 3364
#define PREPB 57                 // ceil(NB*MM / 256) blocks carrying prep work

typedef float f32x4 __attribute__((ext_vector_type(4)));
typedef long  l64x2 __attribute__((ext_vector_type(2)));

// ---------------------------------------------------------------------------
// Kernel 1: pack desc[b][c][m] (f32) into PAIR-INTERLEAVED MFMA-fragment
// fp8-e4m3 tiles (4 KB per [b][mtile][kt]):
//   addr = tile_base + h*2048 + p*1024 + lane*16
//   bytes [0..8) = frag t=2p   lane data, bytes [8..16) = frag t=2p+1
// where frag t covers m = mtile*128 + h*64 + t*16 + (lane&15),
//                     k = kt*32 + (lane>>4)*8 + e.
// The GEMM thus loads each A/B kt-operand with 2 global_load_dwordx4 per
// lane (16 B sweet spot) straight into registers — no LDS. Tail rows
// zero-filled. FUSED: blocks 0..56 do per-cell prep (homography warp,
// vis 8x8 product, per-block vm partials).
// ---------------------------------------------------------------------------
__global__ __launch_bounds__(256) void pack_prep(
    const float* __restrict__ d1, const float* __restrict__ d2,
    const float* __restrict__ homo, const float* __restrict__ vis,
    unsigned char* __restrict__ p1, unsigned char* __restrict__ p2,
    float2* __restrict__ wg, float* __restrict__ vmarr,
    float* __restrict__ vm_part) {
  __shared__ float tile[32][132];   // [k_local][m_local]; rows 528B (16B-aligned)
  int kt = blockIdx.x, mtile = blockIdx.y, z = blockIdx.z;
  int bid = kt + 8 * (mtile + MT * z);
  int b = z & 3;
  const float* src = ((z >> 2) ? d2 : d1) + (size_t)b * CC * MM + (size_t)(kt * 32) * MM;
  unsigned char* dst = ((z >> 2) ? p2 : p1) + ((size_t)(b * MT + mtile) * 8 + kt) * 4096;
  int tid = threadIdx.x;

  // coalesced read: 32 k-rows x 128 m (float4 along m)
#pragma unroll
  for (int pass = 0; pass < 4; ++pass) {
    int cid = pass * 256 + tid;          // [0,1024)
    int c = cid >> 5, m4 = (cid & 31) * 4;
    int gm = mtile * 128 + m4;
    float4 v;
    if (gm + 3 < MM) {
      v = *(const float4*)(src + (size_t)c * MM + gm);
    } else {
      v.x = (gm     < MM) ? src[(size_t)c * MM + gm]     : 0.f;
      v.y = (gm + 1 < MM) ? src[(size_t)c * MM + gm + 1] : 0.f;
      v.z = (gm + 2 < MM) ? src[(size_t)c * MM + gm + 2] : 0.f;
      v.w = (gm + 3 < MM) ? src[(size_t)c * MM + gm + 3] : 0.f;
    }
    *(float4*)&tile[c][m4] = v;
  }
  __syncthreads();

  // pair-interleaved fragment write: 256 slots x 16B, one pass.
  // slot s: lane = s&63, p = (s>>6)&1, h = s>>7.
  {
    int s = tid;
    int lane = s & 63, p = (s >> 6) & 1, h = s >> 7;
    int k_local = (lane >> 4) * 8;
    uint4 o;
    unsigned ww[4];
#pragma unroll
    for (int j = 0; j < 2; ++j) {
      int m_local = h * 64 + (2 * p + j) * 16 + (lane & 15);
      unsigned w01 = 0, w23 = 0;
      if (mtile * 128 + m_local < MM) {
        float f0 = tile[k_local + 0][m_local], f1 = tile[k_local + 1][m_local];
        float f2 = tile[k_local + 2][m_local], f3 = tile[k_local + 3][m_local];
        float f4 = tile[k_local + 4][m_local], f5 = tile[k_local + 5][m_local];
        float f6 = tile[k_local + 6][m_local], f7 = tile[k_local + 7][m_local];
        w01 = __builtin_amdgcn_cvt_pk_fp8_f32(f0, f1, 0, false);
        w01 = __builtin_amdgcn_cvt_pk_fp8_f32(f2, f3, w01, true);
        w23 = __builtin_amdgcn_cvt_pk_fp8_f32(f4, f5, 0, false);
        w23 = __builtin_amdgcn_cvt_pk_fp8_f32(f6, f7, w23, true);
      }
      ww[2 * j]     = w01;
      ww[2 * j + 1] = w23;
    }
    o.x = ww[0]; o.y = ww[1]; o.z = ww[2]; o.w = ww[3];
    ((uint4*)dst)[s] = o;
  }

  // ---- fused prep (blocks 0..56 only; block-uniform branch) ----
  if (bid < PREPB) {
    int idx = bid * 256 + tid;
    float p = 0.f;
    if (idx < NB * MM) {
      int bb = idx / MM, cell = idx - bb * MM;
      int h1 = cell / WR, w1 = cell - h1 * WR;
      float gx = (float)(w1 * GS + GS / 2);
      float gy = (float)(h1 * GS + GS / 2);
      const float* Hm = homo + bb * 9;
      float X = Hm[0] * gx + Hm[1] * gy + Hm[2];
      float Y = Hm[3] * gx + Hm[4] * gy + Hm[5];
      float Z = Hm[6] * gx + Hm[7] * gy + Hm[8];
      wg[idx] = make_float2(X / Z, Y / Z);
      const float* v = vis + (size_t)bb * HH * WW + (size_t)(h1 * GS) * WW + w1 * GS;
      float prod = 1.f;
#pragma unroll
      for (int rr = 0; rr < GS; ++rr) {
        const float4* rp = (const float4*)(v + (size_t)rr * WW);
        float4 a = rp[0], c = rp[1];
        prod *= a.x * a.y * a.z * a.w;
        prod *= c.x * c.y * c.z * c.w;
      }
      vmarr[idx] = prod;
      p = prod;
    }
#pragma unroll
    for (int off = 32; off; off >>= 1) p += __shfl_down(p, off, 64);
    __syncthreads();                      // tile LDS reuse safety
    if ((tid & 63) == 0) ((float*)tile)[tid >> 6] = p;
    __syncthreads();
    if (tid == 0)
      vm_part[bid] = ((float*)tile)[0] + ((float*)tile)[1] +
                     ((float*)tile)[2] + ((float*)tile)[3];
  }
}

// ---------------------------------------------------------------------------
// Kernel 2: fp8 MFMA GEMM + hinge loss. No LDS staging, no K-loop barriers,
// no contended atomics (blocks write private partial slots).
// launch_bounds(256,4): 128-reg/wave budget — acc[4][4] lives in AGPRs with
// zero spill (round 8's (256,8) halved the budget and spilled acc to
// scratch: 1.5 GB traffic, 305 us — never again). Pair-interleaved
// fragments: 2 dwordx4 loads per lane per operand per kt.
// ---------------------------------------------------------------------------
__global__ __launch_bounds__(256, 4) void hinge_gemm(
    const unsigned char* __restrict__ Ap, const unsigned char* __restrict__ Bp,
    const float2* __restrict__ wg, const float* __restrict__ vmarr,
    float* __restrict__ block_part) {
  __shared__ float partial[4];

  int b = blockIdx.z, mtile = blockIdx.y, ntile = blockIdx.x;
  int tid = threadIdx.x, lane = tid & 63, w = tid >> 6;
  int quad = lane >> 4, r = lane & 15;
  int wave_m = w >> 1, wave_n = w & 1;

  // per-lane fragment-pair base: pair p of kt at base + kt*4096 + p*1024
  const char* Af = (const char*)Ap + ((size_t)(b * MT + mtile) * 8) * 4096
                   + wave_m * 2048 + lane * 16;
  const char* Bf = (const char*)Bp + ((size_t)(b * MT + ntile) * 8) * 4096
                   + wave_n * 2048 + lane * 16;

  f32x4 acc[4][4];
#pragma unroll
  for (int i = 0; i < 4; ++i)
#pragma unroll
    for (int j = 0; j < 4; ++j)
#pragma unroll
      for (int k = 0; k < 4; ++k) acc[i][j][k] = 0.f;

  long a0[4], b0[4], a1[4], b1[4];
#pragma unroll
  for (int p = 0; p < 2; ++p) {
    l64x2 va = *(const l64x2*)(Af + p * 1024);
    l64x2 vb = *(const l64x2*)(Bf + p * 1024);
    a0[2 * p] = va.x; a0[2 * p + 1] = va.y;
    b0[2 * p] = vb.x; b0[2 * p + 1] = vb.y;
  }

#pragma unroll
  for (int kt = 0; kt < 8; ++kt) {
    if (kt < 7) {   // prefetch kt+1 fragment-pairs into shadow registers
      const char* an = Af + (kt + 1) * 4096;
      const char* bn = Bf + (kt + 1) * 4096;
#pragma unroll
      for (int p = 0; p < 2; ++p) {
        l64x2 va = *(const l64x2*)(an + p * 1024);
        l64x2 vb = *(const l64x2*)(bn + p * 1024);
        a1[2 * p] = va.x; a1[2 * p + 1] = va.y;
        b1[2 * p] = vb.x; b1[2 * p + 1] = vb.y;
      }
    }
#pragma unroll
    for (int mt = 0; mt < 4; ++mt)
#pragma unroll
      for (int nt = 0; nt < 4; ++nt)
        acc[mt][nt] = __builtin_amdgcn_mfma_f32_16x16x32_fp8_fp8(
            a0[mt], b0[nt], acc[mt][nt], 0, 0, 0);
#pragma unroll
    for (int t = 0; t < 4; ++t) { a0[t] = a1[t]; b0[t] = b1[t]; }
  }

  // Epilogue. C/D layout: col(n) = lane&15, row(m) = quad*4 + reg.
  // Tail m-rows are zero-padded in Ap -> dot=0 -> hinge=0; no m-guard needed.
  float gxv[16], gyv[16];
#pragma unroll
  for (int mt = 0; mt < 4; ++mt)
#pragma unroll
    for (int reg = 0; reg < 4; ++reg) {
      int gm = mtile * 128 + wave_m * 64 + mt * 16 + quad * 4 + reg;
      float gmf = (float)gm;
      float h1 = floorf(fmaf(gmf, (1.0f / 60.0f), (1.0f / 120.0f)));
      float w1 = fmaf(h1, -60.f, gmf);
      gxv[mt * 4 + reg] = fmaf(w1, 8.f, 4.f);
      gyv[mt * 4 + reg] = fmaf(h1, 8.f, 4.f);
    }

  float sum = 0.f;
  const float2* wgb = wg + (size_t)b * MM;
  const float*  vmb = vmarr + (size_t)b * MM;
#pragma unroll
  for (int nt = 0; nt < 4; ++nt) {
    int gn = ntile * 128 + wave_n * 64 + nt * 16 + r;
    bool nok = gn < MM;
    float2 wgv = nok ? wgb[gn] : make_float2(1e9f, 1e9f);
    float  vmv = nok ? vmb[gn] : 0.f;
#pragma unroll
    for (int mt = 0; mt < 4; ++mt)
#pragma unroll
      for (int reg = 0; reg < 4; ++reg) {
        float dot = acc[mt][nt][reg];
        float dx = gxv[mt * 4 + reg] - wgv.x;
        float dy = gyv[mt * 4 + reg] - wgv.y;
        float d2 = fmaf(dx, dx, dy * dy);
        float a = (d2 <= 56.25f) ? (1.0f - dot) : (dot - 0.2f);
        sum = fmaf(vmv, fmaxf(a, 0.f), sum);
      }
  }
#pragma unroll
  for (int off = 32; off; off >>= 1) sum += __shfl_down(sum, off, 64);
  if (lane == 0) partial[w] = sum;
  __syncthreads();
  if (tid == 0) {
    int fbid = ntile + MT * (mtile + MT * b);
    block_part[fbid] = partial[0] + partial[1] + partial[2] + partial[3];
  }
}

// ---------------------------------------------------------------------------
// Kernel 3: reduce 3364 block partials + 57 vm partials; write output.
// ---------------------------------------------------------------------------
__global__ __launch_bounds__(256) void finalize_k(
    const float* __restrict__ block_part, const float* __restrict__ vm_part,
    float* __restrict__ out) {
  __shared__ float red[8];
  int tid = threadIdx.x;
  float s = 0.f, v = 0.f;
  for (int i = tid; i < NBLK; i += 256) s += block_part[i];
  if (tid < PREPB) v = vm_part[tid];
#pragma unroll
  for (int off = 32; off; off >>= 1) {
    s += __shfl_down(s, off, 64);
    v += __shfl_down(v, off, 64);
  }
  if ((tid & 63) == 0) { red[tid >> 6] = s; red[4 + (tid >> 6)] = v; }
  __syncthreads();
  if (tid == 0) {
    float S = red[0] + red[1] + red[2] + red[3];
    float V = red[4] + red[5] + red[6] + red[7];
    out[0] = S / ((float)MM * V);
  }
}

extern "C" void kernel_launch(void* const* d_in, const int* in_sizes, int n_in,
                              void* d_out, int out_size, void* d_ws, size_t ws_size,
                              hipStream_t stream) {
  const float* desc1 = (const float*)d_in[0];
  const float* desc2 = (const float*)d_in[1];
  const float* homo  = (const float*)d_in[2];
  const float* vis   = (const float*)d_in[3];
  float* out = (float*)d_out;

  char* ws = (char*)d_ws;
  // packed size per desc: 4 * 29 * 8 * 4096 B = 3,801,088 B
  unsigned char* Ap = (unsigned char*)ws;
  unsigned char* Bp = (unsigned char*)(ws + 3801088);
  float2* wg         = (float2*)(ws + 7602176);          // 115,200 B
  float*  vm         = (float*) (ws + 7717376);          //  57,600 B
  float*  vm_part    = (float*) (ws + 7774976);          // 57 * 4 B
  float*  block_part = (float*) (ws + 7775232);          // 3364 * 4 B

  dim3 pgrid(8, MT, 2 * NB);   // kt x mtile x (desc,b); fused prep
  pack_prep<<<pgrid, 256, 0, stream>>>(desc1, desc2, homo, vis, Ap, Bp,
                                       wg, vm, vm_part);

  dim3 ggrid(MT, MT, NB);
  hinge_gemm<<<ggrid, 256, 0, stream>>>(Ap, Bp, wg, vm, block_part);

  finalize_k<<<1, 256, 0, stream>>>(block_part, vm_part, out);
}

// Round 10
// 116.933 us; speedup vs baseline: 3.2517x; 1.0063x over previous
//
#include <hip/hip_runtime.h>
#include <stdint.h>

// Problem constants (from reference)
#define NB   4      // batch
#define CC   256    // channels (K)
#define WR   60     // cells per row/col
#define MM   3600   // HR*WR (M and N of the GEMM)
#define HH   480
#define WW   480
#define GS   8
#define MT   29     // ceil(3600/128) tiles per side
#define NBLK (MT * MT * NB)      // gemm grid size = 3364
#define PREPB 57                 // ceil(NB*MM / 256) blocks carrying prep work

typedef float f32x4 __attribute__((ext_vector_type(4)));
typedef long  l64x2 __attribute__((ext_vector_type(2)));

// ---------------------------------------------------------------------------
// Kernel 1: pack desc[b][c][m] (f32) into PAIR-INTERLEAVED MFMA-fragment
// fp8-e4m3 tiles (4 KB per [b][mtile][kt]):
//   addr = tile_base + h*2048 + p*1024 + lane*16
//   bytes [0..8) = frag t=2p lane data, bytes [8..16) = frag t=2p+1
// where frag t covers m = mtile*128 + h*64 + t*16 + (lane&15),
//                     k = kt*32 + (lane>>4)*8 + e.
// Round-10: NO LDS stage (the old transpose's read phase had a provable
// 4-way bank conflict: 132-float rows put all 4 quads on the same 16
// banks). Each thread gathers its 16 values directly from global: for a
// given (e,j) the 16 lanes of a quad read 16 consecutive floats = one
// 64-B line, each line touched exactly once. No barriers in the pack.
// Tail rows zero-filled. FUSED: blocks 0..56 do per-cell prep.
// ---------------------------------------------------------------------------
__global__ __launch_bounds__(256) void pack_prep(
    const float* __restrict__ d1, const float* __restrict__ d2,
    const float* __restrict__ homo, const float* __restrict__ vis,
    unsigned char* __restrict__ p1, unsigned char* __restrict__ p2,
    float2* __restrict__ wg, float* __restrict__ vmarr,
    float* __restrict__ vm_part) {
  __shared__ float vmred[4];
  int kt = blockIdx.x, mtile = blockIdx.y, z = blockIdx.z;
  int bid = kt + 8 * (mtile + MT * z);
  int b = z & 3;
  const float* src = ((z >> 2) ? d2 : d1) + (size_t)b * CC * MM + (size_t)(kt * 32) * MM;
  unsigned char* dst = ((z >> 2) ? p2 : p1) + ((size_t)(b * MT + mtile) * 8 + kt) * 4096;
  int tid = threadIdx.x;
  int lane = tid & 63, pp = (tid >> 6) & 1, h = tid >> 7;
  int r = lane & 15;
  int k0 = (lane >> 4) * 8;

  unsigned ww[4];
#pragma unroll
  for (int j = 0; j < 2; ++j) {
    int gm = mtile * 128 + h * 64 + (2 * pp + j) * 16 + r;
    unsigned w01 = 0, w23 = 0;
    if (gm < MM) {
      const float* s0 = src + (size_t)k0 * MM + gm;
      float f0 = s0[0 * MM], f1 = s0[1 * MM], f2 = s0[2 * MM], f3 = s0[3 * MM];
      float f4 = s0[4 * MM], f5 = s0[5 * MM], f6 = s0[6 * MM], f7 = s0[7 * MM];
      w01 = __builtin_amdgcn_cvt_pk_fp8_f32(f0, f1, 0, false);
      w01 = __builtin_amdgcn_cvt_pk_fp8_f32(f2, f3, w01, true);
      w23 = __builtin_amdgcn_cvt_pk_fp8_f32(f4, f5, 0, false);
      w23 = __builtin_amdgcn_cvt_pk_fp8_f32(f6, f7, w23, true);
    }
    ww[2 * j]     = w01;
    ww[2 * j + 1] = w23;
  }
  uint4 o; o.x = ww[0]; o.y = ww[1]; o.z = ww[2]; o.w = ww[3];
  ((uint4*)dst)[tid] = o;

  // ---- fused prep (blocks 0..56 only; block-uniform branch) ----
  if (bid < PREPB) {
    int idx = bid * 256 + tid;
    float p = 0.f;
    if (idx < NB * MM) {
      int bb = idx / MM, cell = idx - bb * MM;
      int h1 = cell / WR, w1 = cell - h1 * WR;
      float gx = (float)(w1 * GS + GS / 2);
      float gy = (float)(h1 * GS + GS / 2);
      const float* Hm = homo + bb * 9;
      float X = Hm[0] * gx + Hm[1] * gy + Hm[2];
      float Y = Hm[3] * gx + Hm[4] * gy + Hm[5];
      float Z = Hm[6] * gx + Hm[7] * gy + Hm[8];
      wg[idx] = make_float2(X / Z, Y / Z);
      const float* v = vis + (size_t)bb * HH * WW + (size_t)(h1 * GS) * WW + w1 * GS;
      float prod = 1.f;
#pragma unroll
      for (int rr = 0; rr < GS; ++rr) {
        const float4* rp = (const float4*)(v + (size_t)rr * WW);
        float4 a = rp[0], c = rp[1];
        prod *= a.x * a.y * a.z * a.w;
        prod *= c.x * c.y * c.z * c.w;
      }
      vmarr[idx] = prod;
      p = prod;
    }
#pragma unroll
    for (int off = 32; off; off >>= 1) p += __shfl_down(p, off, 64);
    if ((tid & 63) == 0) vmred[tid >> 6] = p;
    __syncthreads();
    if (tid == 0)
      vm_part[bid] = vmred[0] + vmred[1] + vmred[2] + vmred[3];
  }
}

// ---------------------------------------------------------------------------
// Kernel 2: fp8 MFMA GEMM + hinge loss. No LDS staging, no K-loop barriers,
// no contended atomics (blocks write private partial slots).
// launch_bounds(256,4): 128-reg/wave budget — acc[4][4] lives in AGPRs with
// zero spill (a (256,8) bound spills acc to scratch: 1.5 GB traffic —
// never again). Pair-interleaved fragments: 2 dwordx4 loads per lane per
// operand per kt, register double-buffered (prefetch distance 1).
// ---------------------------------------------------------------------------
__global__ __launch_bounds__(256, 4) void hinge_gemm(
    const unsigned char* __restrict__ Ap, const unsigned char* __restrict__ Bp,
    const float2* __restrict__ wg, const float* __restrict__ vmarr,
    float* __restrict__ block_part) {
  __shared__ float partial[4];

  int b = blockIdx.z, mtile = blockIdx.y, ntile = blockIdx.x;
  int tid = threadIdx.x, lane = tid & 63, w = tid >> 6;
  int quad = lane >> 4, r = lane & 15;
  int wave_m = w >> 1, wave_n = w & 1;

  // per-lane fragment-pair base: pair p of kt at base + kt*4096 + p*1024
  const char* Af = (const char*)Ap + ((size_t)(b * MT + mtile) * 8) * 4096
                   + wave_m * 2048 + lane * 16;
  const char* Bf = (const char*)Bp + ((size_t)(b * MT + ntile) * 8) * 4096
                   + wave_n * 2048 + lane * 16;

  f32x4 acc[4][4];
#pragma unroll
  for (int i = 0; i < 4; ++i)
#pragma unroll
    for (int j = 0; j < 4; ++j)
#pragma unroll
      for (int k = 0; k < 4; ++k) acc[i][j][k] = 0.f;

  long a0[4], b0[4], a1[4], b1[4];
#pragma unroll
  for (int p = 0; p < 2; ++p) {
    l64x2 va = *(const l64x2*)(Af + p * 1024);
    l64x2 vb = *(const l64x2*)(Bf + p * 1024);
    a0[2 * p] = va.x; a0[2 * p + 1] = va.y;
    b0[2 * p] = vb.x; b0[2 * p + 1] = vb.y;
  }

#pragma unroll
  for (int kt = 0; kt < 8; ++kt) {
    if (kt < 7) {   // prefetch kt+1 fragment-pairs into shadow registers
      const char* an = Af + (kt + 1) * 4096;
      const char* bn = Bf + (kt + 1) * 4096;
#pragma unroll
      for (int p = 0; p < 2; ++p) {
        l64x2 va = *(const l64x2*)(an + p * 1024);
        l64x2 vb = *(const l64x2*)(bn + p * 1024);
        a1[2 * p] = va.x; a1[2 * p + 1] = va.y;
        b1[2 * p] = vb.x; b1[2 * p + 1] = vb.y;
      }
    }
#pragma unroll
    for (int mt = 0; mt < 4; ++mt)
#pragma unroll
      for (int nt = 0; nt < 4; ++nt)
        acc[mt][nt] = __builtin_amdgcn_mfma_f32_16x16x32_fp8_fp8(
            a0[mt], b0[nt], acc[mt][nt], 0, 0, 0);
#pragma unroll
    for (int t = 0; t < 4; ++t) { a0[t] = a1[t]; b0[t] = b1[t]; }
  }

  // Epilogue. C/D layout: col(n) = lane&15, row(m) = quad*4 + reg.
  // Tail m-rows are zero-padded in Ap -> dot=0 -> hinge=0; no m-guard needed.
  float gxv[16], gyv[16];
#pragma unroll
  for (int mt = 0; mt < 4; ++mt)
#pragma unroll
    for (int reg = 0; reg < 4; ++reg) {
      int gm = mtile * 128 + wave_m * 64 + mt * 16 + quad * 4 + reg;
      float gmf = (float)gm;
      float h1 = floorf(fmaf(gmf, (1.0f / 60.0f), (1.0f / 120.0f)));
      float w1 = fmaf(h1, -60.f, gmf);
      gxv[mt * 4 + reg] = fmaf(w1, 8.f, 4.f);
      gyv[mt * 4 + reg] = fmaf(h1, 8.f, 4.f);
    }

  float sum = 0.f;
  const float2* wgb = wg + (size_t)b * MM;
  const float*  vmb = vmarr + (size_t)b * MM;
#pragma unroll
  for (int nt = 0; nt < 4; ++nt) {
    int gn = ntile * 128 + wave_n * 64 + nt * 16 + r;
    bool nok = gn < MM;
    float2 wgv = nok ? wgb[gn] : make_float2(1e9f, 1e9f);
    float  vmv = nok ? vmb[gn] : 0.f;
#pragma unroll
    for (int mt = 0; mt < 4; ++mt)
#pragma unroll
      for (int reg = 0; reg < 4; ++reg) {
        float dot = acc[mt][nt][reg];
        float dx = gxv[mt * 4 + reg] - wgv.x;
        float dy = gyv[mt * 4 + reg] - wgv.y;
        float d2 = fmaf(dx, dx, dy * dy);
        float a = (d2 <= 56.25f) ? (1.0f - dot) : (dot - 0.2f);
        sum = fmaf(vmv, fmaxf(a, 0.f), sum);
      }
  }
#pragma unroll
  for (int off = 32; off; off >>= 1) sum += __shfl_down(sum, off, 64);
  if (lane == 0) partial[w] = sum;
  __syncthreads();
  if (tid == 0) {
    int fbid = ntile + MT * (mtile + MT * b);
    block_part[fbid] = partial[0] + partial[1] + partial[2] + partial[3];
  }
}

// ---------------------------------------------------------------------------
// Kernel 3: reduce 3364 block partials + 57 vm partials; write output.
// ---------------------------------------------------------------------------
__global__ __launch_bounds__(256) void finalize_k(
    const float* __restrict__ block_part, const float* __restrict__ vm_part,
    float* __restrict__ out) {
  __shared__ float red[8];
  int tid = threadIdx.x;
  float s = 0.f, v = 0.f;
  for (int i = tid; i < NBLK; i += 256) s += block_part[i];
  if (tid < PREPB) v = vm_part[tid];
#pragma unroll
  for (int off = 32; off; off >>= 1) {
    s += __shfl_down(s, off, 64);
    v += __shfl_down(v, off, 64);
  }
  if ((tid & 63) == 0) { red[tid >> 6] = s; red[4 + (tid >> 6)] = v; }
  __syncthreads();
  if (tid == 0) {
    float S = red[0] + red[1] + red[2] + red[3];
    float V = red[4] + red[5] + red[6] + red[7];
    out[0] = S / ((float)MM * V);
  }
}

extern "C" void kernel_launch(void* const* d_in, const int* in_sizes, int n_in,
                              void* d_out, int out_size, void* d_ws, size_t ws_size,
                              hipStream_t stream) {
  const float* desc1 = (const float*)d_in[0];
  const float* desc2 = (const float*)d_in[1];
  const float* homo  = (const float*)d_in[2];
  const float* vis   = (const float*)d_in[3];
  float* out = (float*)d_out;

  char* ws = (char*)d_ws;
  // packed size per desc: 4 * 29 * 8 * 4096 B = 3,801,088 B
  unsigned char* Ap = (unsigned char*)ws;
  unsigned char* Bp = (unsigned char*)(ws + 3801088);
  float2* wg         = (float2*)(ws + 7602176);          // 115,200 B
  float*  vm         = (float*) (ws + 7717376);          //  57,600 B
  float*  vm_part    = (float*) (ws + 7774976);          // 57 * 4 B
  float*  block_part = (float*) (ws + 7775232);          // 3364 * 4 B

  dim3 pgrid(8, MT, 2 * NB);   // kt x mtile x (desc,b); fused prep
  pack_prep<<<pgrid, 256, 0, stream>>>(desc1, desc2, homo, vis, Ap, Bp,
                                       wg, vm, vm_part);

  dim3 ggrid(MT, MT, NB);
  hinge_gemm<<<ggrid, 256, 0, stream>>>(Ap, Bp, wg, vm, block_part);

  finalize_k<<<1, 256, 0, stream>>>(block_part, vm_part, out);
}